// Round 14
// baseline (8856.676 us; speedup 1.0000x reference)
//
#include <hip/hip_runtime.h>
#include <hip/hip_bf16.h>

#define BB 32
#define TT 512
#define IND 375
#define DD 512
#define HH 8
#define HDD 64
#define LL 6
#define FFNN 1024
#define LATD 256
#define KCODES 512
#define DLL 4
#define DHH 512
#define DFFF 1024
#define OUTD 291
#define MTOK (BB*TT)   /* 16384 tokens */
#define KPAD 384       /* padded K for input proj */
#define NPAD 384       /* padded N for output proj */

typedef short short8v __attribute__((ext_vector_type(8)));
typedef float float4v __attribute__((ext_vector_type(4)));

__device__ __forceinline__ unsigned short f2bf(float f) {
  unsigned int u = __float_as_uint(f);
  unsigned int r = (u + 0x7FFFu + ((u >> 16) & 1u)) >> 16;
  return (unsigned short)r;
}
__device__ __forceinline__ float bf2f(unsigned short s) {
  return __uint_as_float(((unsigned int)s) << 16);
}

// ---------------- RoPE tables (fp32) ----------------
__global__ void rope_table_k(float* __restrict__ cosb, float* __restrict__ sinb) {
  int idx = blockIdx.x * blockDim.x + threadIdx.x;
  if (idx >= TT * 32) return;
  int t = idx >> 5, i = idx & 31;
  float inv = powf(10000.0f, -(float)(2 * i) / 64.0f);
  float f = (float)t * inv;
  cosb[idx] = cosf(f);
  sinb[idx] = sinf(f);
}

// ---------------- padding kernels (zero-pad is numerically exact) ----------------
__global__ void pad_x_k(const float* __restrict__ x, float* __restrict__ Xp) {
  int m = blockIdx.x;
  const float* src = x + (size_t)m * IND;
  float* dst = Xp + (size_t)m * KPAD;
  for (int k = threadIdx.x; k < KPAD; k += 256)
    dst[k] = (k < IND) ? src[k] : 0.0f;
}
__global__ void pad_wx_k(const float* __restrict__ w, float* __restrict__ Wp) {
  int e = blockIdx.x * 256 + threadIdx.x;
  if (e >= KPAD * DD) return;
  int k = e >> 9, n = e & 511;
  Wp[e] = (k < IND) ? w[(size_t)k * DD + n] : 0.0f;
}
__global__ void pad_wo_k(const float* __restrict__ w, const float* __restrict__ b,
                         float* __restrict__ Wp, float* __restrict__ bp) {
  int e = blockIdx.x * 256 + threadIdx.x;
  if (e >= DHH * NPAD) return;
  int k = e / NPAD, n = e - k * NPAD;
  Wp[e] = (n < OUTD) ? w[(size_t)k * OUTD + n] : 0.0f;
  if (e < NPAD) bp[e] = (e < OUTD) ? b[e] : 0.0f;
}
__global__ void unpad_k(const float* __restrict__ Cp, float* __restrict__ out) {
  int m = blockIdx.x;
  const float* src = Cp + (size_t)m * NPAD;
  float* dst = out + (size_t)m * OUTD;
  for (int n = threadIdx.x; n < OUTD; n += 256)
    dst[n] = src[n];
}

// ===== weight 3-split + transpose: w [K][N] fp32 -> 3 planes [N][K] bf16 =====
__global__ void wsplit3_k(const float* __restrict__ w, unsigned short* __restrict__ o,
                          size_t planeSz, int K, int N) {
  int e = blockIdx.x * 256 + threadIdx.x;
  if (e >= K * N) return;
  int k = e / N, n = e - k * N;
  float a = w[e];
  unsigned short h0 = f2bf(a);
  float r = a - bf2f(h0);
  unsigned short h1 = f2bf(r);
  float r2 = r - bf2f(h1);
  unsigned short h2 = f2bf(r2);
  size_t off = (size_t)n * K + k;
  o[off] = h0;
  o[planeSz + off] = h1;
  o[2 * planeSz + off] = h2;
}

// ---------------- fp32 GEMM, 128x128 tile, BK=32 (fallback path) ----------------
template<int EPI>
__global__ __launch_bounds__(256) void gemm128_k(const float* __restrict__ A,
                                                 const float* __restrict__ W,
                                                 const float* __restrict__ bias,
                                                 const float* __restrict__ R,
                                                 float* __restrict__ C,
                                                 int M, int K, int N,
                                                 const float* __restrict__ COS,
                                                 const float* __restrict__ SIN) {
  __shared__ float As[32][128];
  __shared__ float4 Bs4[32][2][16];
  const int bn = blockIdx.x * 128;
  const int bm = blockIdx.y * 128;
  const int tid = threadIdx.x;
  const int tx = tid & 15;
  const int ty = tid >> 4;
  const int ar = tid >> 1;
  const int ak = (tid & 1) * 16;
  const int bk = tid >> 3;
  const int bxs = tid & 7;

  float acc[8][8] = {};

  for (int k0 = 0; k0 < K; k0 += 32) {
    const float* ap = A + (size_t)(bm + ar) * K + k0 + ak;
    float4 a0 = *(const float4*)ap;
    float4 a1 = *(const float4*)(ap + 4);
    float4 a2 = *(const float4*)(ap + 8);
    float4 a3 = *(const float4*)(ap + 12);
    const float* bp = W + (size_t)(k0 + bk) * N + bn + bxs * 16;
    float4 b0 = *(const float4*)bp;
    float4 b1 = *(const float4*)(bp + 4);
    float4 b2 = *(const float4*)(bp + 8);
    float4 b3 = *(const float4*)(bp + 12);

    __syncthreads();
    As[ak +  0][ar] = a0.x; As[ak +  1][ar] = a0.y; As[ak +  2][ar] = a0.z; As[ak +  3][ar] = a0.w;
    As[ak +  4][ar] = a1.x; As[ak +  5][ar] = a1.y; As[ak +  6][ar] = a1.z; As[ak +  7][ar] = a1.w;
    As[ak +  8][ar] = a2.x; As[ak +  9][ar] = a2.y; As[ak + 10][ar] = a2.z; As[ak + 11][ar] = a2.w;
    As[ak + 12][ar] = a3.x; As[ak + 13][ar] = a3.y; As[ak + 14][ar] = a3.z; As[ak + 15][ar] = a3.w;
    Bs4[bk][0][2 * bxs]     = b0;
    Bs4[bk][1][2 * bxs]     = b1;
    Bs4[bk][0][2 * bxs + 1] = b2;
    Bs4[bk][1][2 * bxs + 1] = b3;
    __syncthreads();

#pragma unroll
    for (int kk = 0; kk < 32; ++kk) {
      float4 va0 = *(const float4*)&As[kk][ty * 8];
      float4 va1 = *(const float4*)&As[kk][ty * 8 + 4];
      float4 vb0 = Bs4[kk][0][tx];
      float4 vb1 = Bs4[kk][1][tx];
      float av[8] = {va0.x, va0.y, va0.z, va0.w, va1.x, va1.y, va1.z, va1.w};
      float bv[8] = {vb0.x, vb0.y, vb0.z, vb0.w, vb1.x, vb1.y, vb1.z, vb1.w};
#pragma unroll
      for (int ii = 0; ii < 8; ++ii)
#pragma unroll
        for (int jj = 0; jj < 8; ++jj)
          acc[ii][jj] = __builtin_fmaf(av[ii], bv[jj], acc[ii][jj]);
    }
  }

#pragma unroll
  for (int ii = 0; ii < 8; ++ii) {
    int m = bm + ty * 8 + ii;
#pragma unroll
    for (int g = 0; g < 2; ++g) {
      int n0 = bn + tx * 8 + g * 4;
      float t4[4];
#pragma unroll
      for (int j = 0; j < 4; ++j) {
        float v = acc[ii][g * 4 + j] + bias[n0 + j];
        if (EPI == 1) v += R[(size_t)m * N + n0 + j];
        if (EPI == 2) v = 0.5f * v * (1.0f + erff(v * 0.70710678118654752f));
        t4[j] = v;
      }
      if (EPI == 3 && n0 < 2 * DD) {
        int tpos = m & 511;
        int i0 = (n0 & 63) >> 1;
        float c0 = COS[tpos * 32 + i0],     s0 = SIN[tpos * 32 + i0];
        float c1 = COS[tpos * 32 + i0 + 1], s1 = SIN[tpos * 32 + i0 + 1];
        float xe0 = t4[0], xo0 = t4[1], xe1 = t4[2], xo1 = t4[3];
        t4[0] = xe0 * c0 - xo0 * s0;
        t4[1] = xe0 * s0 + xo0 * c0;
        t4[2] = xe1 * c1 - xo1 * s1;
        t4[3] = xe1 * s1 + xo1 * c1;
      }
      float4 vv; vv.x = t4[0]; vv.y = t4[1]; vv.z = t4[2]; vv.w = t4[3];
      *(float4*)&C[(size_t)m * N + n0] = vv;
    }
  }
}

// ===== bf16x6 MFMA GEMM (full-precision 3-term split): C = A*W + bias =====
// B pre-split to 3 planes [N][K] bf16 (BT, BT+planeSz, BT+2*planeSz).
// A split to 3 bf16 terms in staging. 6 MFMA products cover error <= 2^-27.
// tile 128x128, K-step 32, 4 waves x 64x64. M%128==0, N%128==0, K%32==0.
// frag layout verified in round 13: A lane l elem j = A[l&15][(l>>4)*8+j];
// B (as [N][K]) lane l elem j = BT[l&15][(l>>4)*8+j]; D reg r -> row=(l>>4)*4+r, col=l&15.
// EPI: 0 bias, 1 +residual, 2 gelu, 3 +fused RoPE (cross-lane pair via shfl_xor 1)
template<int EPI>
__global__ __launch_bounds__(256) void bgemm6_k(const float* __restrict__ A,
                                                const unsigned short* __restrict__ BT,
                                                size_t planeSz,
                                                const float* __restrict__ bias,
                                                const float* __restrict__ R,
                                                float* __restrict__ C,
                                                int M, int K, int N,
                                                const float* __restrict__ COS,
                                                const float* __restrict__ SIN) {
  __shared__ unsigned short A0s[128][40], A1s[128][40], A2s[128][40];
  __shared__ unsigned short B0s[128][40], B1s[128][40], B2s[128][40];
  const int bn = blockIdx.x * 128;
  const int bm = blockIdx.y * 128;
  const int tid = threadIdx.x;
  const int w = tid >> 6, lane = tid & 63;
  const int wm = (w >> 1) * 64, wn = (w & 1) * 64;
  const int lr = lane & 15;
  const int kh = lane >> 4;
  const int sr = tid >> 1;
  const int sk = (tid & 1) * 16;

  float4v acc[4][4] = {};

  for (int k0 = 0; k0 < K; k0 += 32) {
    const float* ap = A + (size_t)(bm + sr) * K + k0 + sk;
    float av[16];
#pragma unroll
    for (int q = 0; q < 4; ++q) {
      float4 v = *(const float4*)(ap + q * 4);
      av[q * 4 + 0] = v.x; av[q * 4 + 1] = v.y; av[q * 4 + 2] = v.z; av[q * 4 + 3] = v.w;
    }
    const unsigned short* b0p = BT + (size_t)(bn + sr) * K + k0 + sk;
    uint4 b00 = *(const uint4*)b0p, b01 = *(const uint4*)(b0p + 8);
    const unsigned short* b1p = b0p + planeSz;
    uint4 b10 = *(const uint4*)b1p, b11 = *(const uint4*)(b1p + 8);
    const unsigned short* b2p = b1p + planeSz;
    uint4 b20 = *(const uint4*)b2p, b21 = *(const uint4*)(b2p + 8);

    __syncthreads();   // previous tile fully consumed
    unsigned int w0[8], w1[8], w2[8];
#pragma unroll
    for (int q = 0; q < 8; ++q) {
      float aa = av[2 * q], ab = av[2 * q + 1];
      unsigned short h0a = f2bf(aa); float ra = aa - bf2f(h0a);
      unsigned short h1a = f2bf(ra); float r2a = ra - bf2f(h1a);
      unsigned short h2a = f2bf(r2a);
      unsigned short h0b = f2bf(ab); float rb = ab - bf2f(h0b);
      unsigned short h1b = f2bf(rb); float r2b = rb - bf2f(h1b);
      unsigned short h2b = f2bf(r2b);
      w0[q] = (unsigned int)h0a | ((unsigned int)h0b << 16);
      w1[q] = (unsigned int)h1a | ((unsigned int)h1b << 16);
      w2[q] = (unsigned int)h2a | ((unsigned int)h2b << 16);
    }
    *(uint4*)&A0s[sr][sk]     = make_uint4(w0[0], w0[1], w0[2], w0[3]);
    *(uint4*)&A0s[sr][sk + 8] = make_uint4(w0[4], w0[5], w0[6], w0[7]);
    *(uint4*)&A1s[sr][sk]     = make_uint4(w1[0], w1[1], w1[2], w1[3]);
    *(uint4*)&A1s[sr][sk + 8] = make_uint4(w1[4], w1[5], w1[6], w1[7]);
    *(uint4*)&A2s[sr][sk]     = make_uint4(w2[0], w2[1], w2[2], w2[3]);
    *(uint4*)&A2s[sr][sk + 8] = make_uint4(w2[4], w2[5], w2[6], w2[7]);
    *(uint4*)&B0s[sr][sk]     = b00;  *(uint4*)&B0s[sr][sk + 8] = b01;
    *(uint4*)&B1s[sr][sk]     = b10;  *(uint4*)&B1s[sr][sk + 8] = b11;
    *(uint4*)&B2s[sr][sk]     = b20;  *(uint4*)&B2s[sr][sk + 8] = b21;
    __syncthreads();

    short8v b0f[4], b1f[4], b2f[4];
#pragma unroll
    for (int nt = 0; nt < 4; ++nt) {
      b0f[nt] = *(const short8v*)&B0s[wn + nt * 16 + lr][kh * 8];
      b1f[nt] = *(const short8v*)&B1s[wn + nt * 16 + lr][kh * 8];
      b2f[nt] = *(const short8v*)&B2s[wn + nt * 16 + lr][kh * 8];
    }
#pragma unroll
    for (int mt = 0; mt < 4; ++mt) {
      short8v a0f = *(const short8v*)&A0s[wm + mt * 16 + lr][kh * 8];
      short8v a1f = *(const short8v*)&A1s[wm + mt * 16 + lr][kh * 8];
      short8v a2f = *(const short8v*)&A2s[wm + mt * 16 + lr][kh * 8];
#pragma unroll
      for (int nt = 0; nt < 4; ++nt) {
        acc[mt][nt] = __builtin_amdgcn_mfma_f32_16x16x32_bf16(a0f, b0f[nt], acc[mt][nt], 0, 0, 0);
        acc[mt][nt] = __builtin_amdgcn_mfma_f32_16x16x32_bf16(a0f, b1f[nt], acc[mt][nt], 0, 0, 0);
        acc[mt][nt] = __builtin_amdgcn_mfma_f32_16x16x32_bf16(a1f, b0f[nt], acc[mt][nt], 0, 0, 0);
        acc[mt][nt] = __builtin_amdgcn_mfma_f32_16x16x32_bf16(a0f, b2f[nt], acc[mt][nt], 0, 0, 0);
        acc[mt][nt] = __builtin_amdgcn_mfma_f32_16x16x32_bf16(a1f, b1f[nt], acc[mt][nt], 0, 0, 0);
        acc[mt][nt] = __builtin_amdgcn_mfma_f32_16x16x32_bf16(a2f, b0f[nt], acc[mt][nt], 0, 0, 0);
      }
    }
  }

#pragma unroll
  for (int mt = 0; mt < 4; ++mt) {
#pragma unroll
    for (int nt = 0; nt < 4; ++nt) {
      int col = bn + wn + nt * 16 + (lane & 15);
#pragma unroll
      for (int r = 0; r < 4; ++r) {
        int row = bm + wm + mt * 16 + (lane >> 4) * 4 + r;
        float v = acc[mt][nt][r] + bias[col];
        if (EPI == 1) v += R[(size_t)row * N + col];
        if (EPI == 2) v = 0.5f * v * (1.0f + erff(v * 0.70710678118654752f));
        if (EPI == 3) {
          float p = __shfl_xor(v, 1);
          if (col < 2 * DD) {
            int tpos = row & 511;
            int i0 = (col & 63) >> 1;
            float c = COS[tpos * 32 + i0], s = SIN[tpos * 32 + i0];
            v = ((col & 1) == 0) ? (v * c - p * s) : (p * s + v * c);
          }
        }
        C[(size_t)row * N + col] = v;
      }
    }
  }
}

// ---------------- LayerNorm over D=512, wave per row ----------------
__global__ __launch_bounds__(256) void ln_k(const float* __restrict__ X,
                                            const float* __restrict__ s,
                                            const float* __restrict__ b,
                                            float* __restrict__ Y) {
  int wave = threadIdx.x >> 6, lane = threadIdx.x & 63;
  int row = blockIdx.x * 4 + wave;
  const float* x = X + (size_t)row * DD;
  float v[8];
  float sum = 0.0f;
#pragma unroll
  for (int j = 0; j < 8; ++j) { v[j] = x[lane + 64 * j]; sum += v[j]; }
#pragma unroll
  for (int o = 32; o; o >>= 1) sum += __shfl_xor(sum, o);
  float mean = sum * (1.0f / 512.0f);
  float var = 0.0f;
#pragma unroll
  for (int j = 0; j < 8; ++j) { float d = v[j] - mean; var += d * d; }
#pragma unroll
  for (int o = 32; o; o >>= 1) var += __shfl_xor(var, o);
  float inv = 1.0f / sqrtf(var * (1.0f / 512.0f) + 1e-5f);
  float* y = Y + (size_t)row * DD;
#pragma unroll
  for (int j = 0; j < 8; ++j) {
    int d = lane + 64 * j;
    y[d] = (v[j] - mean) * inv * s[d] + b[d];
  }
}

// ---------------- flash attention: block = (b, h, 64 q-rows), XCD-grouped ------
__global__ __launch_bounds__(256) void fattn_k(const float* __restrict__ qkv,
                                               float* __restrict__ out) {
  __shared__ float Qs[64][68];
  __shared__ float KVs[64][68];
  __shared__ float Ps[64][68];
  const int tid = threadIdx.x;
  const int tx = tid & 15, ty = tid >> 4;
  const int g = blockIdx.x;
  const int xcd = g & 7, slot = g >> 3;
  const int qt = slot & 7;
  const int p = ((slot >> 3) << 3) | xcd;
  const int h = p & 7;
  const int b = p >> 3;
  const float* base = qkv + (size_t)b * TT * (3 * DD) + h * HDD;

  {
    int r = tid & 63, q0 = tid >> 6;
#pragma unroll
    for (int jj = 0; jj < 4; ++jj) {
      int q = q0 + jj * 4;
      float4 v = *(const float4*)(base + (size_t)(qt * 64 + r) * (3 * DD) + q * 4);
      Qs[q * 4 + 0][r] = v.x; Qs[q * 4 + 1][r] = v.y;
      Qs[q * 4 + 2][r] = v.z; Qs[q * 4 + 3][r] = v.w;
    }
  }

  float o[4][4] = {};
  float m[4] = {-1e30f, -1e30f, -1e30f, -1e30f};
  float l[4] = {0.f, 0.f, 0.f, 0.f};

  for (int kt = 0; kt < 8; ++kt) {
    __syncthreads();
    {
      int r = tid & 63, q0 = tid >> 6;
#pragma unroll
      for (int jj = 0; jj < 4; ++jj) {
        int q = q0 + jj * 4;
        float4 v = *(const float4*)(base + (size_t)(kt * 64 + r) * (3 * DD) + DD + q * 4);
        KVs[q * 4 + 0][r] = v.x; KVs[q * 4 + 1][r] = v.y;
        KVs[q * 4 + 2][r] = v.z; KVs[q * 4 + 3][r] = v.w;
      }
    }
    __syncthreads();

    float s[4][4] = {};
#pragma unroll 4
    for (int d = 0; d < 64; ++d) {
      float4 a4 = *(const float4*)&Qs[d][ty * 4];
      float4 b4 = *(const float4*)&KVs[d][tx * 4];
      float av[4] = {a4.x, a4.y, a4.z, a4.w};
      float bv[4] = {b4.x, b4.y, b4.z, b4.w};
#pragma unroll
      for (int ii = 0; ii < 4; ++ii)
#pragma unroll
        for (int jj = 0; jj < 4; ++jj)
          s[ii][jj] = __builtin_fmaf(av[ii], bv[jj], s[ii][jj]);
    }

#pragma unroll
    for (int i = 0; i < 4; ++i) {
      float mm = fmaxf(fmaxf(s[i][0], s[i][1]), fmaxf(s[i][2], s[i][3])) * 0.125f;
#pragma unroll
      for (int off = 1; off < 16; off <<= 1) mm = fmaxf(mm, __shfl_xor(mm, off));
      float mn = fmaxf(m[i], mm);
      float f = expf(m[i] - mn);
      m[i] = mn;
      float ls = 0.0f;
#pragma unroll
      for (int j = 0; j < 4; ++j) {
        float pp = expf(__builtin_fmaf(s[i][j], 0.125f, -mn));
        s[i][j] = pp;
        ls += pp;
      }
#pragma unroll
      for (int off = 1; off < 16; off <<= 1) ls += __shfl_xor(ls, off);
      l[i] = __builtin_fmaf(l[i], f, ls);
#pragma unroll
      for (int j = 0; j < 4; ++j) o[i][j] *= f;
    }

    __syncthreads();

#pragma unroll
    for (int j = 0; j < 4; ++j) {
      float4 pv; pv.x = s[0][j]; pv.y = s[1][j]; pv.z = s[2][j]; pv.w = s[3][j];
      *(float4*)&Ps[tx * 4 + j][ty * 4] = pv;
    }
#pragma unroll
    for (int ii = 0; ii < 4; ++ii) {
      int e = tid + 256 * ii;
      int c = e >> 4, q = e & 15;
      float4 v = *(const float4*)(base + (size_t)(kt * 64 + c) * (3 * DD) + 2 * DD + q * 4);
      *(float4*)&KVs[c][q * 4] = v;
    }
    __syncthreads();

#pragma unroll 4
    for (int c = 0; c < 64; ++c) {
      float4 a4 = *(const float4*)&Ps[c][ty * 4];
      float4 b4 = *(const float4*)&KVs[c][tx * 4];
      float av[4] = {a4.x, a4.y, a4.z, a4.w};
      float bv[4] = {b4.x, b4.y, b4.z, b4.w};
#pragma unroll
      for (int ii = 0; ii < 4; ++ii)
#pragma unroll
        for (int jj = 0; jj < 4; ++jj)
          o[ii][jj] = __builtin_fmaf(av[ii], bv[jj], o[ii][jj]);
    }
  }

#pragma unroll
  for (int i = 0; i < 4; ++i) {
    float inv = 1.0f / l[i];
    int tok = b * TT + qt * 64 + ty * 4 + i;
    float4 vv;
    vv.x = o[i][0] * inv; vv.y = o[i][1] * inv;
    vv.z = o[i][2] * inv; vv.w = o[i][3] * inv;
    *(float4*)&out[(size_t)tok * DD + h * HDD + tx * 4] = vv;
  }
}

// ===== numpy pairwise-8 sum of squares (strict fp32 order) =====
__device__ __forceinline__ float npsumsq64(const float* __restrict__ a) {
  float r0 = __fmul_rn(a[0], a[0]), r1 = __fmul_rn(a[1], a[1]);
  float r2 = __fmul_rn(a[2], a[2]), r3 = __fmul_rn(a[3], a[3]);
  float r4 = __fmul_rn(a[4], a[4]), r5 = __fmul_rn(a[5], a[5]);
  float r6 = __fmul_rn(a[6], a[6]), r7 = __fmul_rn(a[7], a[7]);
#pragma unroll
  for (int i = 8; i < 64; i += 8) {
    r0 = __fadd_rn(r0, __fmul_rn(a[i + 0], a[i + 0]));
    r1 = __fadd_rn(r1, __fmul_rn(a[i + 1], a[i + 1]));
    r2 = __fadd_rn(r2, __fmul_rn(a[i + 2], a[i + 2]));
    r3 = __fadd_rn(r3, __fmul_rn(a[i + 3], a[i + 3]));
    r4 = __fadd_rn(r4, __fmul_rn(a[i + 4], a[i + 4]));
    r5 = __fadd_rn(r5, __fmul_rn(a[i + 5], a[i + 5]));
    r6 = __fadd_rn(r6, __fmul_rn(a[i + 6], a[i + 6]));
    r7 = __fadd_rn(r7, __fmul_rn(a[i + 7], a[i + 7]));
  }
  return __fadd_rn(__fadd_rn(__fadd_rn(r0, r1), __fadd_rn(r2, r3)),
                   __fadd_rn(__fadd_rn(r4, r5), __fadd_rn(r6, r7)));
}

// ===== S2 precompute =====
__global__ void vqs2_k(const float* __restrict__ CB, float* __restrict__ S2) {
  int k = blockIdx.x * 256 + threadIdx.x;
  if (k < KCODES) S2[k] = npsumsq64(CB + (size_t)k * 64);
}

// ===== VQ argmin (bit-identical numpy fp32 formula): 16 chunks / block =====
__global__ __launch_bounds__(256) void vq32b_k(const float* __restrict__ Z,
                                               const float* __restrict__ CB,
                                               const float* __restrict__ S2,
                                               int* __restrict__ idxOut) {
  __shared__ float zs[16][68];
  __shared__ float cs[64][68];
  __shared__ float s2s[64];
  __shared__ float rv[256];
  __shared__ int   ri[256];
  const int tid = threadIdx.x;
  const int lr = tid >> 4;
  const int sub = tid & 15;
  const int row0 = blockIdx.x * 16;

  {
    int r = tid >> 4, q = tid & 15;
    *(float4*)&zs[r][q * 4] = *(const float4*)(Z + (size_t)(row0 + r) * 64 + q * 4);
  }
  __syncthreads();

  const float S1 = npsumsq64(zs[lr]);

  float bv = 3.4e38f;
  int bi = 0x7fffffff;
  for (int ct = 0; ct < 8; ++ct) {
    __syncthreads();
    for (int e = tid; e < 1024; e += 256) {
      int r = e >> 4, q = e & 15;
      *(float4*)&cs[r][q * 4] = *(const float4*)(CB + (size_t)(ct * 64 + r) * 64 + q * 4);
    }
    if (tid < 64) s2s[tid] = S2[ct * 64 + tid];
    __syncthreads();
#pragma unroll
    for (int cc = 0; cc < 4; ++cc) {
      int kl = cc * 16 + sub;
      float g = 0.0f;
#pragma unroll
      for (int d4 = 0; d4 < 16; ++d4) {
        float4 zf = *(const float4*)&zs[lr][d4 * 4];
        float4 cf = *(const float4*)&cs[kl][d4 * 4];
        g = __builtin_fmaf(zf.x, cf.x, g);
        g = __builtin_fmaf(zf.y, cf.y, g);
        g = __builtin_fmaf(zf.z, cf.z, g);
        g = __builtin_fmaf(zf.w, cf.w, g);
      }
      float d32 = __fadd_rn(__fsub_rn(S1, __fmul_rn(2.0f, g)), s2s[kl]);
      int k = ct * 64 + kl;
      if (d32 < bv || (d32 == bv && k < bi)) { bv = d32; bi = k; }
    }
  }
  rv[tid] = bv; ri[tid] = bi;
  __syncthreads();
  if (sub == 0) {
    float bb = rv[tid]; int ii = ri[tid];
#pragma unroll
    for (int j = 1; j < 16; ++j) {
      float v = rv[tid + j]; int id = ri[tid + j];
      if (v < bb || (v == bb && id < ii)) { bb = v; ii = id; }
    }
    idxOut[row0 + lr] = ii;
  }
}

// ===== straight-through gather =====
__global__ void stgather_k(const float* __restrict__ Z, const float* __restrict__ CB,
                           const int* __restrict__ idx, float* __restrict__ Q) {
  int e = blockIdx.x * blockDim.x + threadIdx.x;
  if (e >= MTOK * LATD) return;
  int chunk = e >> 6, d = e & 63;
  int k = idx[chunk] & (KCODES - 1);
  float z = Z[e];
  float c = CB[(size_t)k * 64 + d];
  Q[e] = __fadd_rn(z, __fsub_rn(c, z));
}

static inline dim3 g128(int M, int N) { return dim3(N / 128, M / 128); }

extern "C" void kernel_launch(void* const* d_in, const int* in_sizes, int n_in,
                              void* d_out, int out_size, void* d_ws, size_t ws_size,
                              hipStream_t stream) {
  const float* x        = (const float*)d_in[0];
  const float* in_w     = (const float*)d_in[1];
  const float* in_b     = (const float*)d_in[2];
  const float* ln1_s    = (const float*)d_in[3];
  const float* ln1_b    = (const float*)d_in[4];
  const float* qkv_w    = (const float*)d_in[5];
  const float* qkv_b    = (const float*)d_in[6];
  const float* aout_w   = (const float*)d_in[7];
  const float* aout_b   = (const float*)d_in[8];
  const float* ln2_s    = (const float*)d_in[9];
  const float* ln2_b    = (const float*)d_in[10];
  const float* ff1_w    = (const float*)d_in[11];
  const float* ff1_b    = (const float*)d_in[12];
  const float* ff2_w    = (const float*)d_in[13];
  const float* ff2_b    = (const float*)d_in[14];
  const float* lat_w    = (const float*)d_in[15];
  const float* lat_b    = (const float*)d_in[16];
  const float* codebook = (const float*)d_in[17];
  const float* unlat_w  = (const float*)d_in[18];
  const float* unlat_b  = (const float*)d_in[19];
  const float* dln_s    = (const float*)d_in[20];
  const float* dln_b    = (const float*)d_in[21];
  const float* dff1_w   = (const float*)d_in[22];
  const float* dff1_b   = (const float*)d_in[23];
  const float* dff2_w   = (const float*)d_in[24];
  const float* dff2_b   = (const float*)d_in[25];
  const float* ow       = (const float*)d_in[26];
  const float* ob       = (const float*)d_in[27];
  float* out = (float*)d_out;

  float* ws   = (float*)d_ws;
  float* Hb   = ws;
  float* Yb   = Hb + (size_t)MTOK * DD;
  float* QKVb = Yb + (size_t)MTOK * DD;
  float* COSb = QKVb + (size_t)MTOK * 3 * DD;
  float* SINb = COSb + TT * 32;
  int*   IDXb = (int*)(SINb + TT * 32);
  float* S2b  = (float*)(IDXb + MTOK * 4);
  float* WXp  = S2b + KCODES;
  float* WOp  = WXp + (size_t)KPAD * DD;
  float* BOp  = WOp + (size_t)DHH * NPAD;
  float* Xp   = QKVb;
  float* Cp   = QKVb;

  // bf16x3 split-weight planes (ushort), 16B-aligned
  uintptr_t ua = ((uintptr_t)(BOp + NPAD) + 15) & ~(uintptr_t)15;
  unsigned short* Uw = (unsigned short*)ua;
  const size_t QWp = (size_t)(3 * DD) * DD;     // 1536*512
  const size_t AWp = (size_t)DD * DD;           // 512*512
  const size_t F1p = (size_t)DFFF * DHH;        // 1024*512
  const size_t F2p = (size_t)DHH * DFFF;        // 512*1024
  const size_t INp = (size_t)DD * KPAD;         // 512*384
  const size_t LTp = (size_t)LATD * DD;         // 256*512
  const size_t UWp = (size_t)DHH * LATD;        // 512*256
  const size_t OWp = (size_t)NPAD * DHH;        // 384*512
  unsigned short* QW  = Uw;
  unsigned short* AW  = QW  + 6 * 3 * QWp;
  unsigned short* F1  = AW  + 6 * 3 * AWp;
  unsigned short* F2  = F1  + 6 * 3 * F1p;
  unsigned short* INW = F2  + 6 * 3 * F2p;
  unsigned short* LTW = INW + 3 * INp;
  unsigned short* UW  = LTW + 3 * LTp;
  unsigned short* D1  = UW  + 3 * UWp;
  unsigned short* D2  = D1  + 4 * 3 * F1p;
  unsigned short* OW  = D2  + 4 * 3 * F2p;
  size_t need = (size_t)((char*)(OW + 3 * OWp) - (char*)d_ws) + 64;
  const bool mf = ws_size >= need;

  dim3 blk(256);

  rope_table_k<<<(TT * 32 + 255) / 256, blk, 0, stream>>>(COSb, SINb);
  vqs2_k<<<2, blk, 0, stream>>>(codebook, S2b);
  pad_wx_k<<<(KPAD * DD + 255) / 256, blk, 0, stream>>>(in_w, WXp);
  pad_wo_k<<<(DHH * NPAD + 255) / 256, blk, 0, stream>>>(ow, ob, WOp, BOp);
  pad_x_k<<<MTOK, blk, 0, stream>>>(x, Xp);

  if (mf) {
    // ---- one-time weight splits ----
    for (int l = 0; l < LL; ++l) {
      wsplit3_k<<<(int)((DD * 3 * DD + 255) / 256), blk, 0, stream>>>(
          qkv_w + (size_t)l * DD * 3 * DD, QW + (size_t)l * 3 * QWp, QWp, DD, 3 * DD);
      wsplit3_k<<<(int)((DD * DD + 255) / 256), blk, 0, stream>>>(
          aout_w + (size_t)l * DD * DD, AW + (size_t)l * 3 * AWp, AWp, DD, DD);
      wsplit3_k<<<(int)((DD * FFNN + 255) / 256), blk, 0, stream>>>(
          ff1_w + (size_t)l * DD * FFNN, F1 + (size_t)l * 3 * F1p, F1p, DD, FFNN);
      wsplit3_k<<<(int)((FFNN * DD + 255) / 256), blk, 0, stream>>>(
          ff2_w + (size_t)l * FFNN * DD, F2 + (size_t)l * 3 * F2p, F2p, FFNN, DD);
    }
    wsplit3_k<<<(int)((KPAD * DD + 255) / 256), blk, 0, stream>>>(WXp, INW, INp, KPAD, DD);
    wsplit3_k<<<(int)((DD * LATD + 255) / 256), blk, 0, stream>>>(lat_w, LTW, LTp, DD, LATD);
    wsplit3_k<<<(int)((LATD * DHH + 255) / 256), blk, 0, stream>>>(unlat_w, UW, UWp, LATD, DHH);
    for (int l = 0; l < DLL; ++l) {
      wsplit3_k<<<(int)((DHH * DFFF + 255) / 256), blk, 0, stream>>>(
          dff1_w + (size_t)l * DHH * DFFF, D1 + (size_t)l * 3 * F1p, F1p, DHH, DFFF);
      wsplit3_k<<<(int)((DFFF * DHH + 255) / 256), blk, 0, stream>>>(
          dff2_w + (size_t)l * DFFF * DHH, D2 + (size_t)l * 3 * F2p, F2p, DFFF, DHH);
    }
    wsplit3_k<<<(int)((DHH * NPAD + 255) / 256), blk, 0, stream>>>(WOp, OW, OWp, DHH, NPAD);

    // ---- encoder (bf16x6 MFMA) ----
    bgemm6_k<0><<<g128(MTOK, DD), blk, 0, stream>>>(Xp, INW, INp, in_b, nullptr, Hb,
                                                    MTOK, KPAD, DD, nullptr, nullptr);
    for (int l = 0; l < LL; ++l) {
      ln_k<<<MTOK / 4, blk, 0, stream>>>(Hb, ln1_s + l * DD, ln1_b + l * DD, Yb);
      bgemm6_k<3><<<g128(MTOK, 3 * DD), blk, 0, stream>>>(Yb, QW + (size_t)l * 3 * QWp, QWp,
                                                          qkv_b + l * 3 * DD, nullptr, QKVb,
                                                          MTOK, DD, 3 * DD, COSb, SINb);
      fattn_k<<<BB * HH * (TT / 64), blk, 0, stream>>>(QKVb, Yb);
      bgemm6_k<1><<<g128(MTOK, DD), blk, 0, stream>>>(Yb, AW + (size_t)l * 3 * AWp, AWp,
                                                      aout_b + l * DD, Hb, Hb, MTOK, DD, DD,
                                                      nullptr, nullptr);
      ln_k<<<MTOK / 4, blk, 0, stream>>>(Hb, ln2_s + l * DD, ln2_b + l * DD, Yb);
      bgemm6_k<2><<<g128(MTOK, FFNN), blk, 0, stream>>>(Yb, F1 + (size_t)l * 3 * F1p, F1p,
                                                        ff1_b + l * FFNN, nullptr, QKVb,
                                                        MTOK, DD, FFNN, nullptr, nullptr);
      bgemm6_k<1><<<g128(MTOK, DD), blk, 0, stream>>>(QKVb, F2 + (size_t)l * 3 * F2p, F2p,
                                                      ff2_b + l * DD, Hb, Hb, MTOK, FFNN, DD,
                                                      nullptr, nullptr);
    }
    bgemm6_k<0><<<g128(MTOK, LATD), blk, 0, stream>>>(Hb, LTW, LTp, lat_b, nullptr, Yb,
                                                      MTOK, DD, LATD, nullptr, nullptr);
    vq32b_k<<<(MTOK * 4) / 16, blk, 0, stream>>>(Yb, codebook, S2b, IDXb);
    stgather_k<<<(MTOK * LATD) / 256, blk, 0, stream>>>(Yb, codebook, IDXb, QKVb);

    // ---- decoder (bf16x6 MFMA) ----
    bgemm6_k<0><<<g128(MTOK, DHH), blk, 0, stream>>>(QKVb, UW, UWp, unlat_b, nullptr, Hb,
                                                     MTOK, LATD, DHH, nullptr, nullptr);
    for (int l = 0; l < DLL; ++l) {
      ln_k<<<MTOK / 4, blk, 0, stream>>>(Hb, dln_s + l * DHH, dln_b + l * DHH, Yb);
      bgemm6_k<2><<<g128(MTOK, DFFF), blk, 0, stream>>>(Yb, D1 + (size_t)l * 3 * F1p, F1p,
                                                        dff1_b + l * DFFF, nullptr, QKVb,
                                                        MTOK, DHH, DFFF, nullptr, nullptr);
      bgemm6_k<1><<<g128(MTOK, DHH), blk, 0, stream>>>(QKVb, D2 + (size_t)l * 3 * F2p, F2p,
                                                       dff2_b + l * DHH, Hb, Hb,
                                                       MTOK, DFFF, DHH, nullptr, nullptr);
    }
    bgemm6_k<0><<<g128(MTOK, NPAD), blk, 0, stream>>>(Hb, OW, OWp, BOp, nullptr, Cp,
                                                      MTOK, DHH, NPAD, nullptr, nullptr);
    unpad_k<<<MTOK, blk, 0, stream>>>(Cp, out);
  } else {
    // ---- fallback: all-fp32 (round-12 flow, proven) ----
    gemm128_k<0><<<g128(MTOK, DD), blk, 0, stream>>>(Xp, WXp, in_b, nullptr, Hb,
                                                     MTOK, KPAD, DD, nullptr, nullptr);
    for (int l = 0; l < LL; ++l) {
      ln_k<<<MTOK / 4, blk, 0, stream>>>(Hb, ln1_s + l * DD, ln1_b + l * DD, Yb);
      gemm128_k<3><<<g128(MTOK, 3 * DD), blk, 0, stream>>>(Yb, qkv_w + (size_t)l * DD * 3 * DD,
                                                           qkv_b + l * 3 * DD, nullptr, QKVb,
                                                           MTOK, DD, 3 * DD, COSb, SINb);
      fattn_k<<<BB * HH * (TT / 64), blk, 0, stream>>>(QKVb, Yb);
      gemm128_k<1><<<g128(MTOK, DD), blk, 0, stream>>>(Yb, aout_w + (size_t)l * DD * DD,
                                                       aout_b + l * DD, Hb, Hb, MTOK, DD, DD,
                                                       nullptr, nullptr);
      ln_k<<<MTOK / 4, blk, 0, stream>>>(Hb, ln2_s + l * DD, ln2_b + l * DD, Yb);
      gemm128_k<2><<<g128(MTOK, FFNN), blk, 0, stream>>>(Yb, ff1_w + (size_t)l * DD * FFNN,
                                                         ff1_b + l * FFNN, nullptr, QKVb,
                                                         MTOK, DD, FFNN, nullptr, nullptr);
      gemm128_k<1><<<g128(MTOK, DD), blk, 0, stream>>>(QKVb, ff2_w + (size_t)l * FFNN * DD,
                                                       ff2_b + l * DD, Hb, Hb, MTOK, FFNN, DD,
                                                       nullptr, nullptr);
    }
    gemm128_k<0><<<g128(MTOK, LATD), blk, 0, stream>>>(Hb, lat_w, lat_b, nullptr, Yb,
                                                       MTOK, DD, LATD, nullptr, nullptr);
    vq32b_k<<<(MTOK * 4) / 16, blk, 0, stream>>>(Yb, codebook, S2b, IDXb);
    stgather_k<<<(MTOK * LATD) / 256, blk, 0, stream>>>(Yb, codebook, IDXb, QKVb);
    gemm128_k<0><<<g128(MTOK, DHH), blk, 0, stream>>>(QKVb, unlat_w, unlat_b, nullptr, Hb,
                                                      MTOK, LATD, DHH, nullptr, nullptr);
    for (int l = 0; l < DLL; ++l) {
      ln_k<<<MTOK / 4, blk, 0, stream>>>(Hb, dln_s + l * DHH, dln_b + l * DHH, Yb);
      gemm128_k<2><<<g128(MTOK, DFFF), blk, 0, stream>>>(Yb, dff1_w + (size_t)l * DHH * DFFF,
                                                         dff1_b + l * DFFF, nullptr, QKVb,
                                                         MTOK, DHH, DFFF, nullptr, nullptr);
      gemm128_k<1><<<g128(MTOK, DHH), blk, 0, stream>>>(QKVb, dff2_w + (size_t)l * DFFF * DHH,
                                                        dff2_b + l * DHH, Hb, Hb,
                                                        MTOK, DFFF, DHH, nullptr, nullptr);
    }
    gemm128_k<0><<<g128(MTOK, NPAD), blk, 0, stream>>>(Hb, WOp, BOp, nullptr, Cp,
                                                       MTOK, DHH, NPAD, nullptr, nullptr);
    unpad_k<<<MTOK, blk, 0, stream>>>(Cp, out);
  }
}

// Round 16
// 7805.019 us; speedup vs baseline: 1.1347x; 1.1347x over previous
//
#include <hip/hip_runtime.h>
#include <hip/hip_bf16.h>

#define BB 32
#define TT 512
#define IND 375
#define DD 512
#define HH 8
#define HDD 64
#define LL 6
#define FFNN 1024
#define LATD 256
#define KCODES 512
#define DLL 4
#define DHH 512
#define DFFF 1024
#define OUTD 291
#define MTOK (BB*TT)   /* 16384 tokens */
#define KPAD 384       /* padded K for input proj */
#define NPAD 384       /* padded N for output proj */

typedef short short8v __attribute__((ext_vector_type(8)));
typedef float float4v __attribute__((ext_vector_type(4)));

__device__ __forceinline__ unsigned short f2bf(float f) {
  unsigned int u = __float_as_uint(f);
  unsigned int r = (u + 0x7FFFu + ((u >> 16) & 1u)) >> 16;
  return (unsigned short)r;
}
__device__ __forceinline__ float bf2f(unsigned short s) {
  return __uint_as_float(((unsigned int)s) << 16);
}

// ---------------- RoPE tables (fp32) ----------------
__global__ void rope_table_k(float* __restrict__ cosb, float* __restrict__ sinb) {
  int idx = blockIdx.x * blockDim.x + threadIdx.x;
  if (idx >= TT * 32) return;
  int t = idx >> 5, i = idx & 31;
  float inv = powf(10000.0f, -(float)(2 * i) / 64.0f);
  float f = (float)t * inv;
  cosb[idx] = cosf(f);
  sinb[idx] = sinf(f);
}

// ---------------- padding kernels (zero-pad is numerically exact) ----------------
__global__ void pad_x_k(const float* __restrict__ x, float* __restrict__ Xp) {
  int m = blockIdx.x;
  const float* src = x + (size_t)m * IND;
  float* dst = Xp + (size_t)m * KPAD;
  for (int k = threadIdx.x; k < KPAD; k += 256)
    dst[k] = (k < IND) ? src[k] : 0.0f;
}
__global__ void pad_wx_k(const float* __restrict__ w, float* __restrict__ Wp) {
  int e = blockIdx.x * 256 + threadIdx.x;
  if (e >= KPAD * DD) return;
  int k = e >> 9, n = e & 511;
  Wp[e] = (k < IND) ? w[(size_t)k * DD + n] : 0.0f;
}
__global__ void pad_wo_k(const float* __restrict__ w, const float* __restrict__ b,
                         float* __restrict__ Wp, float* __restrict__ bp) {
  int e = blockIdx.x * 256 + threadIdx.x;
  if (e >= DHH * NPAD) return;
  int k = e / NPAD, n = e - k * NPAD;
  Wp[e] = (n < OUTD) ? w[(size_t)k * OUTD + n] : 0.0f;
  if (e < NPAD) bp[e] = (e < OUTD) ? b[e] : 0.0f;
}
__global__ void unpad_k(const float* __restrict__ Cp, float* __restrict__ out) {
  int m = blockIdx.x;
  const float* src = Cp + (size_t)m * NPAD;
  float* dst = out + (size_t)m * OUTD;
  for (int n = threadIdx.x; n < OUTD; n += 256)
    dst[n] = src[n];
}

// ===== weight split+transpose: w [K][N] fp32 -> hiT, loT [N][K] bf16 =====
__global__ void wsplit_k(const float* __restrict__ w, unsigned short* __restrict__ hiT,
                         unsigned short* __restrict__ loT, int K, int N) {
  int e = blockIdx.x * 256 + threadIdx.x;
  if (e >= K * N) return;
  int k = e / N, n = e - k * N;
  float a = w[e];
  unsigned short h = f2bf(a);
  unsigned short l = f2bf(a - bf2f(h));
  hiT[(size_t)n * K + k] = h;
  loT[(size_t)n * K + k] = l;
}

// ---------------- fp32 GEMM, 128x128 tile, BK=32, 8x8/thread (encoder) ----------
// Bs4 semantic: element [kk][h][t] holds columns n = t*8 + h*4 .. +3.
// EPI: 0 bias, 1 bias+residual, 2 gelu, 3 bias+fused-RoPE (QKV layout)
template<int EPI>
__global__ __launch_bounds__(256) void gemm128_k(const float* __restrict__ A,
                                                 const float* __restrict__ W,
                                                 const float* __restrict__ bias,
                                                 const float* __restrict__ R,
                                                 float* __restrict__ C,
                                                 int M, int K, int N,
                                                 const float* __restrict__ COS,
                                                 const float* __restrict__ SIN) {
  __shared__ float As[32][128];
  __shared__ float4 Bs4[32][2][16];
  const int bn = blockIdx.x * 128;
  const int bm = blockIdx.y * 128;
  const int tid = threadIdx.x;
  const int tx = tid & 15;
  const int ty = tid >> 4;
  const int ar = tid >> 1;
  const int ak = (tid & 1) * 16;
  const int bk = tid >> 3;
  const int bxs = tid & 7;

  float acc[8][8] = {};

  for (int k0 = 0; k0 < K; k0 += 32) {
    const float* ap = A + (size_t)(bm + ar) * K + k0 + ak;
    float4 a0 = *(const float4*)ap;
    float4 a1 = *(const float4*)(ap + 4);
    float4 a2 = *(const float4*)(ap + 8);
    float4 a3 = *(const float4*)(ap + 12);
    const float* bp = W + (size_t)(k0 + bk) * N + bn + bxs * 16;
    float4 b0 = *(const float4*)bp;
    float4 b1 = *(const float4*)(bp + 4);
    float4 b2 = *(const float4*)(bp + 8);
    float4 b3 = *(const float4*)(bp + 12);

    __syncthreads();
    As[ak +  0][ar] = a0.x; As[ak +  1][ar] = a0.y; As[ak +  2][ar] = a0.z; As[ak +  3][ar] = a0.w;
    As[ak +  4][ar] = a1.x; As[ak +  5][ar] = a1.y; As[ak +  6][ar] = a1.z; As[ak +  7][ar] = a1.w;
    As[ak +  8][ar] = a2.x; As[ak +  9][ar] = a2.y; As[ak + 10][ar] = a2.z; As[ak + 11][ar] = a2.w;
    As[ak + 12][ar] = a3.x; As[ak + 13][ar] = a3.y; As[ak + 14][ar] = a3.z; As[ak + 15][ar] = a3.w;
    Bs4[bk][0][2 * bxs]     = b0;
    Bs4[bk][1][2 * bxs]     = b1;
    Bs4[bk][0][2 * bxs + 1] = b2;
    Bs4[bk][1][2 * bxs + 1] = b3;
    __syncthreads();

#pragma unroll
    for (int kk = 0; kk < 32; ++kk) {
      float4 va0 = *(const float4*)&As[kk][ty * 8];
      float4 va1 = *(const float4*)&As[kk][ty * 8 + 4];
      float4 vb0 = Bs4[kk][0][tx];
      float4 vb1 = Bs4[kk][1][tx];
      float av[8] = {va0.x, va0.y, va0.z, va0.w, va1.x, va1.y, va1.z, va1.w};
      float bv[8] = {vb0.x, vb0.y, vb0.z, vb0.w, vb1.x, vb1.y, vb1.z, vb1.w};
#pragma unroll
      for (int ii = 0; ii < 8; ++ii)
#pragma unroll
        for (int jj = 0; jj < 8; ++jj)
          acc[ii][jj] = __builtin_fmaf(av[ii], bv[jj], acc[ii][jj]);
    }
  }

#pragma unroll
  for (int ii = 0; ii < 8; ++ii) {
    int m = bm + ty * 8 + ii;
#pragma unroll
    for (int g = 0; g < 2; ++g) {
      int n0 = bn + tx * 8 + g * 4;
      float t4[4];
#pragma unroll
      for (int j = 0; j < 4; ++j) {
        float v = acc[ii][g * 4 + j] + bias[n0 + j];
        if (EPI == 1) v += R[(size_t)m * N + n0 + j];
        if (EPI == 2) v = 0.5f * v * (1.0f + erff(v * 0.70710678118654752f));
        t4[j] = v;
      }
      if (EPI == 3 && n0 < 2 * DD) {
        int tpos = m & 511;
        int i0 = (n0 & 63) >> 1;
        float c0 = COS[tpos * 32 + i0],     s0 = SIN[tpos * 32 + i0];
        float c1 = COS[tpos * 32 + i0 + 1], s1 = SIN[tpos * 32 + i0 + 1];
        float xe0 = t4[0], xo0 = t4[1], xe1 = t4[2], xo1 = t4[3];
        t4[0] = xe0 * c0 - xo0 * s0;
        t4[1] = xe0 * s0 + xo0 * c0;
        t4[2] = xe1 * c1 - xo1 * s1;
        t4[3] = xe1 * s1 + xo1 * c1;
      }
      float4 vv; vv.x = t4[0]; vv.y = t4[1]; vv.z = t4[2]; vv.w = t4[3];
      *(float4*)&C[(size_t)m * N + n0] = vv;
    }
  }
}

// ===== bf16x3 MFMA GEMM (decoder): C = A*W + bias, W pre-split [N][K] bf16 =====
// A split to (hi,lo) bf16 in staging; D = Ahi*Bhi + Ahi*Blo + Alo*Bhi (fp32 acc).
// tile 128x128, K-step 32, 4 waves each 64x64. M%128==0, N%128==0, K%32==0.
// frag layout (mfma_f32_16x16x32_bf16): A lane l elem j = A[l&15][(l>>4)*8+j];
// B lane l elem j = B[(l>>4)*8+j][l&15]; D lane l reg r = D[(l>>4)*4+r][l&15].
template<int EPI>
__global__ __launch_bounds__(256) void bgemm_k(const float* __restrict__ A,
                                               const unsigned short* __restrict__ BhiT,
                                               const unsigned short* __restrict__ BloT,
                                               const float* __restrict__ bias,
                                               const float* __restrict__ R,
                                               float* __restrict__ C,
                                               int M, int K, int N) {
  __shared__ unsigned short Ah[128][40];
  __shared__ unsigned short Al[128][40];
  __shared__ unsigned short Bh[128][40];
  __shared__ unsigned short Bl[128][40];
  const int bn = blockIdx.x * 128;
  const int bm = blockIdx.y * 128;
  const int tid = threadIdx.x;
  const int w = tid >> 6, lane = tid & 63;
  const int wm = (w >> 1) * 64, wn = (w & 1) * 64;
  const int lr = lane & 15;
  const int kh = lane >> 4;

  const int sr = tid >> 1;
  const int sk = (tid & 1) * 16;

  float4v acc[4][4] = {};

  for (int k0 = 0; k0 < K; k0 += 32) {
    const float* ap = A + (size_t)(bm + sr) * K + k0 + sk;
    float av[16];
#pragma unroll
    for (int q = 0; q < 4; ++q) {
      float4 v = *(const float4*)(ap + q * 4);
      av[q * 4 + 0] = v.x; av[q * 4 + 1] = v.y; av[q * 4 + 2] = v.z; av[q * 4 + 3] = v.w;
    }
    const unsigned short* bph = BhiT + (size_t)(bn + sr) * K + k0 + sk;
    const unsigned short* bpl = BloT + (size_t)(bn + sr) * K + k0 + sk;
    uint4 bh0 = *(const uint4*)bph, bh1 = *(const uint4*)(bph + 8);
    uint4 bl0 = *(const uint4*)bpl, bl1 = *(const uint4*)(bpl + 8);

    __syncthreads();
    unsigned int hw[8], lw[8];
#pragma unroll
    for (int q = 0; q < 8; ++q) {
      unsigned short h0 = f2bf(av[2 * q]);
      unsigned short l0 = f2bf(av[2 * q] - bf2f(h0));
      unsigned short h1 = f2bf(av[2 * q + 1]);
      unsigned short l1 = f2bf(av[2 * q + 1] - bf2f(h1));
      hw[q] = (unsigned int)h0 | ((unsigned int)h1 << 16);
      lw[q] = (unsigned int)l0 | ((unsigned int)l1 << 16);
    }
    *(uint4*)&Ah[sr][sk]     = make_uint4(hw[0], hw[1], hw[2], hw[3]);
    *(uint4*)&Ah[sr][sk + 8] = make_uint4(hw[4], hw[5], hw[6], hw[7]);
    *(uint4*)&Al[sr][sk]     = make_uint4(lw[0], lw[1], lw[2], lw[3]);
    *(uint4*)&Al[sr][sk + 8] = make_uint4(lw[4], lw[5], lw[6], lw[7]);
    *(uint4*)&Bh[sr][sk]     = bh0;
    *(uint4*)&Bh[sr][sk + 8] = bh1;
    *(uint4*)&Bl[sr][sk]     = bl0;
    *(uint4*)&Bl[sr][sk + 8] = bl1;
    __syncthreads();

    short8v bfh[4], bfl[4];
#pragma unroll
    for (int nt = 0; nt < 4; ++nt) {
      bfh[nt] = *(const short8v*)&Bh[wn + nt * 16 + lr][kh * 8];
      bfl[nt] = *(const short8v*)&Bl[wn + nt * 16 + lr][kh * 8];
    }
#pragma unroll
    for (int mt = 0; mt < 4; ++mt) {
      short8v afh = *(const short8v*)&Ah[wm + mt * 16 + lr][kh * 8];
      short8v afl = *(const short8v*)&Al[wm + mt * 16 + lr][kh * 8];
#pragma unroll
      for (int nt = 0; nt < 4; ++nt) {
        acc[mt][nt] = __builtin_amdgcn_mfma_f32_16x16x32_bf16(afh, bfh[nt], acc[mt][nt], 0, 0, 0);
        acc[mt][nt] = __builtin_amdgcn_mfma_f32_16x16x32_bf16(afh, bfl[nt], acc[mt][nt], 0, 0, 0);
        acc[mt][nt] = __builtin_amdgcn_mfma_f32_16x16x32_bf16(afl, bfh[nt], acc[mt][nt], 0, 0, 0);
      }
    }
  }

#pragma unroll
  for (int mt = 0; mt < 4; ++mt) {
#pragma unroll
    for (int nt = 0; nt < 4; ++nt) {
#pragma unroll
      for (int r = 0; r < 4; ++r) {
        int row = bm + wm + mt * 16 + (lane >> 4) * 4 + r;
        int col = bn + wn + nt * 16 + (lane & 15);
        float v = acc[mt][nt][r] + bias[col];
        if (EPI == 1) v += R[(size_t)row * N + col];
        if (EPI == 2) v = 0.5f * v * (1.0f + erff(v * 0.70710678118654752f));
        C[(size_t)row * N + col] = v;
      }
    }
  }
}

// ---------------- LayerNorm over D=512, wave per row ----------------
__global__ __launch_bounds__(256) void ln_k(const float* __restrict__ X,
                                            const float* __restrict__ s,
                                            const float* __restrict__ b,
                                            float* __restrict__ Y) {
  int wave = threadIdx.x >> 6, lane = threadIdx.x & 63;
  int row = blockIdx.x * 4 + wave;
  const float* x = X + (size_t)row * DD;
  float v[8];
  float sum = 0.0f;
#pragma unroll
  for (int j = 0; j < 8; ++j) { v[j] = x[lane + 64 * j]; sum += v[j]; }
#pragma unroll
  for (int o = 32; o; o >>= 1) sum += __shfl_xor(sum, o);
  float mean = sum * (1.0f / 512.0f);
  float var = 0.0f;
#pragma unroll
  for (int j = 0; j < 8; ++j) { float d = v[j] - mean; var += d * d; }
#pragma unroll
  for (int o = 32; o; o >>= 1) var += __shfl_xor(var, o);
  float inv = 1.0f / sqrtf(var * (1.0f / 512.0f) + 1e-5f);
  float* y = Y + (size_t)row * DD;
#pragma unroll
  for (int j = 0; j < 8; ++j) {
    int d = lane + 64 * j;
    y[d] = (v[j] - mean) * inv * s[d] + b[d];
  }
}

// ---------------- flash attention: block = (b, h, 64 q-rows), XCD-grouped ------
__global__ __launch_bounds__(256) void fattn_k(const float* __restrict__ qkv,
                                               float* __restrict__ out) {
  __shared__ float Qs[64][68];
  __shared__ float KVs[64][68];
  __shared__ float Ps[64][68];
  const int tid = threadIdx.x;
  const int tx = tid & 15, ty = tid >> 4;
  const int g = blockIdx.x;
  const int xcd = g & 7, slot = g >> 3;
  const int qt = slot & 7;
  const int p = ((slot >> 3) << 3) | xcd;
  const int h = p & 7;
  const int b = p >> 3;
  const float* base = qkv + (size_t)b * TT * (3 * DD) + h * HDD;

  {
    int r = tid & 63, q0 = tid >> 6;
#pragma unroll
    for (int jj = 0; jj < 4; ++jj) {
      int q = q0 + jj * 4;
      float4 v = *(const float4*)(base + (size_t)(qt * 64 + r) * (3 * DD) + q * 4);
      Qs[q * 4 + 0][r] = v.x; Qs[q * 4 + 1][r] = v.y;
      Qs[q * 4 + 2][r] = v.z; Qs[q * 4 + 3][r] = v.w;
    }
  }

  float o[4][4] = {};
  float m[4] = {-1e30f, -1e30f, -1e30f, -1e30f};
  float l[4] = {0.f, 0.f, 0.f, 0.f};

  for (int kt = 0; kt < 8; ++kt) {
    __syncthreads();
    {
      int r = tid & 63, q0 = tid >> 6;
#pragma unroll
      for (int jj = 0; jj < 4; ++jj) {
        int q = q0 + jj * 4;
        float4 v = *(const float4*)(base + (size_t)(kt * 64 + r) * (3 * DD) + DD + q * 4);
        KVs[q * 4 + 0][r] = v.x; KVs[q * 4 + 1][r] = v.y;
        KVs[q * 4 + 2][r] = v.z; KVs[q * 4 + 3][r] = v.w;
      }
    }
    __syncthreads();

    float s[4][4] = {};
#pragma unroll 4
    for (int d = 0; d < 64; ++d) {
      float4 a4 = *(const float4*)&Qs[d][ty * 4];
      float4 b4 = *(const float4*)&KVs[d][tx * 4];
      float av[4] = {a4.x, a4.y, a4.z, a4.w};
      float bv[4] = {b4.x, b4.y, b4.z, b4.w};
#pragma unroll
      for (int ii = 0; ii < 4; ++ii)
#pragma unroll
        for (int jj = 0; jj < 4; ++jj)
          s[ii][jj] = __builtin_fmaf(av[ii], bv[jj], s[ii][jj]);
    }

#pragma unroll
    for (int i = 0; i < 4; ++i) {
      float mm = fmaxf(fmaxf(s[i][0], s[i][1]), fmaxf(s[i][2], s[i][3])) * 0.125f;
#pragma unroll
      for (int off = 1; off < 16; off <<= 1) mm = fmaxf(mm, __shfl_xor(mm, off));
      float mn = fmaxf(m[i], mm);
      float f = expf(m[i] - mn);
      m[i] = mn;
      float ls = 0.0f;
#pragma unroll
      for (int j = 0; j < 4; ++j) {
        float pp = expf(__builtin_fmaf(s[i][j], 0.125f, -mn));
        s[i][j] = pp;
        ls += pp;
      }
#pragma unroll
      for (int off = 1; off < 16; off <<= 1) ls += __shfl_xor(ls, off);
      l[i] = __builtin_fmaf(l[i], f, ls);
#pragma unroll
      for (int j = 0; j < 4; ++j) o[i][j] *= f;
    }

    __syncthreads();

#pragma unroll
    for (int j = 0; j < 4; ++j) {
      float4 pv; pv.x = s[0][j]; pv.y = s[1][j]; pv.z = s[2][j]; pv.w = s[3][j];
      *(float4*)&Ps[tx * 4 + j][ty * 4] = pv;
    }
#pragma unroll
    for (int ii = 0; ii < 4; ++ii) {
      int e = tid + 256 * ii;
      int c = e >> 4, q = e & 15;
      float4 v = *(const float4*)(base + (size_t)(kt * 64 + c) * (3 * DD) + 2 * DD + q * 4);
      *(float4*)&KVs[c][q * 4] = v;
    }
    __syncthreads();

#pragma unroll 4
    for (int c = 0; c < 64; ++c) {
      float4 a4 = *(const float4*)&Ps[c][ty * 4];
      float4 b4 = *(const float4*)&KVs[c][tx * 4];
      float av[4] = {a4.x, a4.y, a4.z, a4.w};
      float bv[4] = {b4.x, b4.y, b4.z, b4.w};
#pragma unroll
      for (int ii = 0; ii < 4; ++ii)
#pragma unroll
        for (int jj = 0; jj < 4; ++jj)
          o[ii][jj] = __builtin_fmaf(av[ii], bv[jj], o[ii][jj]);
    }
  }

#pragma unroll
  for (int i = 0; i < 4; ++i) {
    float inv = 1.0f / l[i];
    int tok = b * TT + qt * 64 + ty * 4 + i;
    float4 vv;
    vv.x = o[i][0] * inv; vv.y = o[i][1] * inv;
    vv.z = o[i][2] * inv; vv.w = o[i][3] * inv;
    *(float4*)&out[(size_t)tok * DD + h * HDD + tx * 4] = vv;
  }
}

// ===== numpy pairwise-8 sum of squares (strict fp32 order) =====
__device__ __forceinline__ float npsumsq64(const float* __restrict__ a) {
  float r0 = __fmul_rn(a[0], a[0]), r1 = __fmul_rn(a[1], a[1]);
  float r2 = __fmul_rn(a[2], a[2]), r3 = __fmul_rn(a[3], a[3]);
  float r4 = __fmul_rn(a[4], a[4]), r5 = __fmul_rn(a[5], a[5]);
  float r6 = __fmul_rn(a[6], a[6]), r7 = __fmul_rn(a[7], a[7]);
#pragma unroll
  for (int i = 8; i < 64; i += 8) {
    r0 = __fadd_rn(r0, __fmul_rn(a[i + 0], a[i + 0]));
    r1 = __fadd_rn(r1, __fmul_rn(a[i + 1], a[i + 1]));
    r2 = __fadd_rn(r2, __fmul_rn(a[i + 2], a[i + 2]));
    r3 = __fadd_rn(r3, __fmul_rn(a[i + 3], a[i + 3]));
    r4 = __fadd_rn(r4, __fmul_rn(a[i + 4], a[i + 4]));
    r5 = __fadd_rn(r5, __fmul_rn(a[i + 5], a[i + 5]));
    r6 = __fadd_rn(r6, __fmul_rn(a[i + 6], a[i + 6]));
    r7 = __fadd_rn(r7, __fmul_rn(a[i + 7], a[i + 7]));
  }
  return __fadd_rn(__fadd_rn(__fadd_rn(r0, r1), __fadd_rn(r2, r3)),
                   __fadd_rn(__fadd_rn(r4, r5), __fadd_rn(r6, r7)));
}

// ===== S2 precompute =====
__global__ void vqs2_k(const float* __restrict__ CB, float* __restrict__ S2) {
  int k = blockIdx.x * 256 + threadIdx.x;
  if (k < KCODES) S2[k] = npsumsq64(CB + (size_t)k * 64);
}

// ===== VQ argmin (bit-identical numpy fp32 formula): 16 chunks / block =====
__global__ __launch_bounds__(256) void vq32b_k(const float* __restrict__ Z,
                                               const float* __restrict__ CB,
                                               const float* __restrict__ S2,
                                               int* __restrict__ idxOut) {
  __shared__ float zs[16][68];
  __shared__ float cs[64][68];
  __shared__ float s2s[64];
  __shared__ float rv[256];
  __shared__ int   ri[256];
  const int tid = threadIdx.x;
  const int lr = tid >> 4;
  const int sub = tid & 15;
  const int row0 = blockIdx.x * 16;

  {
    int r = tid >> 4, q = tid & 15;
    *(float4*)&zs[r][q * 4] = *(const float4*)(Z + (size_t)(row0 + r) * 64 + q * 4);
  }
  __syncthreads();

  const float S1 = npsumsq64(zs[lr]);

  float bv = 3.4e38f;
  int bi = 0x7fffffff;
  for (int ct = 0; ct < 8; ++ct) {
    __syncthreads();
    for (int e = tid; e < 1024; e += 256) {
      int r = e >> 4, q = e & 15;
      *(float4*)&cs[r][q * 4] = *(const float4*)(CB + (size_t)(ct * 64 + r) * 64 + q * 4);
    }
    if (tid < 64) s2s[tid] = S2[ct * 64 + tid];
    __syncthreads();
#pragma unroll
    for (int cc = 0; cc < 4; ++cc) {
      int kl = cc * 16 + sub;
      float g = 0.0f;
#pragma unroll
      for (int d4 = 0; d4 < 16; ++d4) {
        float4 zf = *(const float4*)&zs[lr][d4 * 4];
        float4 cf = *(const float4*)&cs[kl][d4 * 4];
        g = __builtin_fmaf(zf.x, cf.x, g);
        g = __builtin_fmaf(zf.y, cf.y, g);
        g = __builtin_fmaf(zf.z, cf.z, g);
        g = __builtin_fmaf(zf.w, cf.w, g);
      }
      float d32 = __fadd_rn(__fsub_rn(S1, __fmul_rn(2.0f, g)), s2s[kl]);
      int k = ct * 64 + kl;
      if (d32 < bv || (d32 == bv && k < bi)) { bv = d32; bi = k; }
    }
  }
  rv[tid] = bv; ri[tid] = bi;
  __syncthreads();
  if (sub == 0) {
    float bb = rv[tid]; int ii = ri[tid];
#pragma unroll
    for (int j = 1; j < 16; ++j) {
      float v = rv[tid + j]; int id = ri[tid + j];
      if (v < bb || (v == bb && id < ii)) { bb = v; ii = id; }
    }
    idxOut[row0 + lr] = ii;
  }
}

// ===== straight-through gather =====
__global__ void stgather_k(const float* __restrict__ Z, const float* __restrict__ CB,
                           const int* __restrict__ idx, float* __restrict__ Q) {
  int e = blockIdx.x * blockDim.x + threadIdx.x;
  if (e >= MTOK * LATD) return;
  int chunk = e >> 6, d = e & 63;
  int k = idx[chunk] & (KCODES - 1);
  float z = Z[e];
  float c = CB[(size_t)k * 64 + d];
  Q[e] = __fadd_rn(z, __fsub_rn(c, z));
}

static inline dim3 g128(int M, int N) { return dim3(N / 128, M / 128); }

extern "C" void kernel_launch(void* const* d_in, const int* in_sizes, int n_in,
                              void* d_out, int out_size, void* d_ws, size_t ws_size,
                              hipStream_t stream) {
  const float* x        = (const float*)d_in[0];
  const float* in_w     = (const float*)d_in[1];
  const float* in_b     = (const float*)d_in[2];
  const float* ln1_s    = (const float*)d_in[3];
  const float* ln1_b    = (const float*)d_in[4];
  const float* qkv_w    = (const float*)d_in[5];
  const float* qkv_b    = (const float*)d_in[6];
  const float* aout_w   = (const float*)d_in[7];
  const float* aout_b   = (const float*)d_in[8];
  const float* ln2_s    = (const float*)d_in[9];
  const float* ln2_b    = (const float*)d_in[10];
  const float* ff1_w    = (const float*)d_in[11];
  const float* ff1_b    = (const float*)d_in[12];
  const float* ff2_w    = (const float*)d_in[13];
  const float* ff2_b    = (const float*)d_in[14];
  const float* lat_w    = (const float*)d_in[15];
  const float* lat_b    = (const float*)d_in[16];
  const float* codebook = (const float*)d_in[17];
  const float* unlat_w  = (const float*)d_in[18];
  const float* unlat_b  = (const float*)d_in[19];
  const float* dln_s    = (const float*)d_in[20];
  const float* dln_b    = (const float*)d_in[21];
  const float* dff1_w   = (const float*)d_in[22];
  const float* dff1_b   = (const float*)d_in[23];
  const float* dff2_w   = (const float*)d_in[24];
  const float* dff2_b   = (const float*)d_in[25];
  const float* ow       = (const float*)d_in[26];
  const float* ob       = (const float*)d_in[27];
  float* out = (float*)d_out;

  float* ws   = (float*)d_ws;
  float* Hb   = ws;
  float* Yb   = Hb + (size_t)MTOK * DD;
  float* QKVb = Yb + (size_t)MTOK * DD;
  float* COSb = QKVb + (size_t)MTOK * 3 * DD;
  float* SINb = COSb + TT * 32;
  int*   IDXb = (int*)(SINb + TT * 32);
  float* S2b  = (float*)(IDXb + MTOK * 4);
  float* WXp  = S2b + KCODES;
  float* WOp  = WXp + (size_t)KPAD * DD;
  float* BOp  = WOp + (size_t)DHH * NPAD;
  unsigned short* u0  = (unsigned short*)(BOp + NPAD);
  unsigned short* UH  = u0;
  unsigned short* UL  = UH + (size_t)DHH * LATD;
  unsigned short* F1H = UL + (size_t)DHH * LATD;
  unsigned short* F1L = F1H + (size_t)DLL * DFFF * DHH;
  unsigned short* F2H = F1L + (size_t)DLL * DFFF * DHH;
  unsigned short* F2L = F2H + (size_t)DLL * DHH * DFFF;
  unsigned short* OH  = F2L + (size_t)DLL * DHH * DFFF;
  unsigned short* OL  = OH + (size_t)NPAD * DHH;
  float* Xp = QKVb;
  float* Cp = QKVb;

  dim3 blk(256);

  rope_table_k<<<(TT * 32 + 255) / 256, blk, 0, stream>>>(COSb, SINb);
  vqs2_k<<<2, blk, 0, stream>>>(codebook, S2b);
  pad_wx_k<<<(KPAD * DD + 255) / 256, blk, 0, stream>>>(in_w, WXp);
  pad_wo_k<<<(DHH * NPAD + 255) / 256, blk, 0, stream>>>(ow, ob, WOp, BOp);
  pad_x_k<<<MTOK, blk, 0, stream>>>(x, Xp);

  // decoder weight split+transpose (one-time)
  wsplit_k<<<(LATD * DHH + 255) / 256, blk, 0, stream>>>(unlat_w, UH, UL, LATD, DHH);
  for (int l = 0; l < DLL; ++l) {
    wsplit_k<<<(DHH * DFFF + 255) / 256, blk, 0, stream>>>(
        dff1_w + (size_t)l * DHH * DFFF, F1H + (size_t)l * DFFF * DHH,
        F1L + (size_t)l * DFFF * DHH, DHH, DFFF);
    wsplit_k<<<(DFFF * DHH + 255) / 256, blk, 0, stream>>>(
        dff2_w + (size_t)l * DFFF * DHH, F2H + (size_t)l * DHH * DFFF,
        F2L + (size_t)l * DHH * DFFF, DFFF, DHH);
  }
  wsplit_k<<<(DHH * NPAD + 255) / 256, blk, 0, stream>>>(WOp, OH, OL, DHH, NPAD);

  // input projection on padded operands
  gemm128_k<0><<<g128(MTOK, DD), blk, 0, stream>>>(Xp, WXp, in_b, nullptr, Hb,
                                                   MTOK, KPAD, DD, nullptr, nullptr);

  for (int l = 0; l < LL; ++l) {
    ln_k<<<MTOK / 4, blk, 0, stream>>>(Hb, ln1_s + l * DD, ln1_b + l * DD, Yb);
    gemm128_k<3><<<g128(MTOK, 3 * DD), blk, 0, stream>>>(Yb, qkv_w + (size_t)l * DD * 3 * DD,
                                                         qkv_b + l * 3 * DD, nullptr, QKVb,
                                                         MTOK, DD, 3 * DD, COSb, SINb);
    fattn_k<<<BB * HH * (TT / 64), blk, 0, stream>>>(QKVb, Yb);
    gemm128_k<1><<<g128(MTOK, DD), blk, 0, stream>>>(Yb, aout_w + (size_t)l * DD * DD,
                                                     aout_b + l * DD, Hb, Hb, MTOK, DD, DD,
                                                     nullptr, nullptr);
    ln_k<<<MTOK / 4, blk, 0, stream>>>(Hb, ln2_s + l * DD, ln2_b + l * DD, Yb);
    gemm128_k<2><<<g128(MTOK, FFNN), blk, 0, stream>>>(Yb, ff1_w + (size_t)l * DD * FFNN,
                                                       ff1_b + l * FFNN, nullptr, QKVb,
                                                       MTOK, DD, FFNN, nullptr, nullptr);
    gemm128_k<1><<<g128(MTOK, DD), blk, 0, stream>>>(QKVb, ff2_w + (size_t)l * FFNN * DD,
                                                     ff2_b + l * DD, Hb, Hb, MTOK, FFNN, DD,
                                                     nullptr, nullptr);
  }

  // latent projection: Z into Yb (fp32 — feeds VQ, must stay exact)
  gemm128_k<0><<<g128(MTOK, LATD), blk, 0, stream>>>(Hb, lat_w, lat_b, nullptr, Yb,
                                                     MTOK, DD, LATD, nullptr, nullptr);
  vq32b_k<<<(MTOK * 4) / 16, blk, 0, stream>>>(Yb, codebook, S2b, IDXb);
  stgather_k<<<(MTOK * LATD) / 256, blk, 0, stream>>>(Yb, codebook, IDXb, QKVb);

  // ----- decoder on bf16x3 MFMA -----
  bgemm_k<0><<<g128(MTOK, DHH), blk, 0, stream>>>(QKVb, UH, UL, unlat_b, nullptr, Hb,
                                                  MTOK, LATD, DHH);
  for (int l = 0; l < DLL; ++l) {
    ln_k<<<MTOK / 4, blk, 0, stream>>>(Hb, dln_s + l * DHH, dln_b + l * DHH, Yb);
    bgemm_k<2><<<g128(MTOK, DFFF), blk, 0, stream>>>(Yb, F1H + (size_t)l * DFFF * DHH,
                                                     F1L + (size_t)l * DFFF * DHH,
                                                     dff1_b + l * DFFF, nullptr, QKVb,
                                                     MTOK, DHH, DFFF);
    bgemm_k<1><<<g128(MTOK, DHH), blk, 0, stream>>>(QKVb, F2H + (size_t)l * DHH * DFFF,
                                                    F2L + (size_t)l * DHH * DFFF,
                                                    dff2_b + l * DHH, Hb, Hb,
                                                    MTOK, DFFF, DHH);
  }
  bgemm_k<0><<<g128(MTOK, NPAD), blk, 0, stream>>>(Hb, OH, OL, BOp, nullptr, Cp,
                                                   MTOK, DHH, NPAD);
  unpad_k<<<MTOK, blk, 0, stream>>>(Cp, out);
}